// Round 5
// baseline (148.366 us; speedup 1.0000x reference)
//
#include <hip/hip_runtime.h>

#define T_STEPS 512
#define BATCH   8192
#define CHUNK   16
#define NCHUNK  (T_STEPS / CHUNK)   // 32

typedef float f32x2 __attribute__((ext_vector_type(2)));

__device__ __forceinline__ float rcp_hw(float v)  { return __builtin_amdgcn_rcpf(v); }
__device__ __forceinline__ float exp2_hw(float v) { return __builtin_amdgcn_exp2f(v); }
__device__ __forceinline__ float med3f(float x, float lo, float hi) {
    return __builtin_amdgcn_fmed3f(x, lo, hi);
}

// DPP cross-lane move (VALU pipe). CTRL compile-time.
template<int CTRL>
__device__ __forceinline__ float dpp_mov(float v) {
    return __int_as_float(__builtin_amdgcn_mov_dpp(__float_as_int(v), CTRL, 0xF, 0xF, true));
}
#define QP_BCAST0 0x00   // quad_perm [0,0,0,0]
#define QP_BCAST2 0xAA   // quad_perm [2,2,2,2]
#define QP_SWAP1  0xB1   // quad_perm [1,0,3,2]  (lane^1)
#define ROW_HALF_MIRROR 0x141  // lane^7  -> quad^1 (quad-uniform data)
#define ROW_ROR8        0x128  // lane^8  -> quad^2
#define ROW_MIRROR      0x140  // lane^15 -> quad^3

// one-time head gather: broadcast lane 2K of each 16-lane group
template<int K>
__device__ __forceinline__ float swz16(float v) {
    return __int_as_float(__builtin_amdgcn_ds_swizzle(__float_as_int(v), ((2*K) << 5) | 0x10));
}

// packed FMA with broadcast of b.lo / b.hi (verified R2/R3)
__device__ __forceinline__ void pk_fma_lo(f32x2& d, f32x2 a, f32x2 b) {
    asm("v_pk_fma_f32 %0, %1, %2, %0 op_sel:[0,0,0] op_sel_hi:[1,0,1]" : "+v"(d) : "v"(a), "v"(b));
}
__device__ __forceinline__ void pk_fma_hi(f32x2& d, f32x2 a, f32x2 b) {
    asm("v_pk_fma_f32 %0, %1, %2, %0 op_sel:[0,1,0] op_sel_hi:[1,1,1]" : "+v"(d) : "v"(a), "v"(b));
}
__device__ __forceinline__ void pk_add(f32x2& d, f32x2 a) {
    asm("v_pk_add_f32 %0, %0, %1" : "+v"(d) : "v"(a));
}
// plain elementwise packed ops
__device__ __forceinline__ f32x2 pk_mul_e(f32x2 a, f32x2 b) {
    f32x2 d; asm("v_pk_mul_f32 %0, %1, %2" : "=v"(d) : "v"(a), "v"(b)); return d;
}
__device__ __forceinline__ f32x2 pk_fma_e(f32x2 a, f32x2 b, f32x2 c) {
    f32x2 d; asm("v_pk_fma_f32 %0, %1, %2, %3" : "=v"(d) : "v"(a), "v"(b), "v"(c)); return d;
}

// Eigen-style rational tanh constants (err ~1e-7 on clamp range)
#define TCL 7.99881172180175781f
#define CA1  4.89352455891786e-03f
#define CA3  6.37261928875436e-04f
#define CA5  1.48572235717979e-05f
#define CA7  5.12229709037114e-08f
#define CA9  -8.60467152213735e-11f
#define CA11 2.00018790482477e-13f
#define CA13 -2.76076847742355e-16f
#define CB0  4.89352518554385e-03f
#define CB2  2.26843463243900e-03f
#define CB4  1.18534705686654e-04f
#define CB6  1.19825839466702e-06f

__device__ __forceinline__ float tanh_rat(float xin) {
    const float u = med3f(xin, -TCL, TCL);
    const float z = u * u;
    float P = fmaf(z, CA13, CA11);
    P = fmaf(z, P, CA9); P = fmaf(z, P, CA7); P = fmaf(z, P, CA5);
    P = fmaf(z, P, CA3); P = fmaf(z, P, CA1);
    float Q = fmaf(z, CB6, CB4);
    Q = fmaf(z, Q, CB2); Q = fmaf(z, Q, CB0);
    return u * P * rcp_hw(Q);
}

__global__ __launch_bounds__(256) void lstm_r4_kernel(
    const float* __restrict__ x,   const float* __restrict__ Wih,
    const float* __restrict__ Whh, const float* __restrict__ bih,
    const float* __restrict__ bhh, const float* __restrict__ W1,
    const float* __restrict__ b1v, const float* __restrict__ W2,
    const float* __restrict__ b2v, float* __restrict__ out)
{
    __shared__ float lds[4096];   // 2 buffers x 16 steps x 16 batches x 8 floats

    const int tid  = threadIdx.x;
    const int lane = tid & 63;
    const int s    = lane & 15;        // slot within 16-lane batch group
    const int p    = s & 1;            // 0: gates {i,f}, 1: gates {g,o}
    const int pi   = s >> 1;           // pair index 0..7
    const int q    = (s >> 2) & 3;     // quad within group
    const int d    = (pi < 6) ? pi : pi - 2;
    const int bl   = (tid >> 6) * 4 + (lane >> 4);  // block-local batch 0..15
    const int b    = blockIdx.x * 16 + bl;

    const int r0 = (p ? 12 : 0) + d;   // i or g
    const int r1 = (p ? 18 : 6) + d;   // f or o

    f32x2 wx[6], wh[8], bias2;
    #pragma unroll
    for (int k = 0; k < 6; ++k) { wx[k].x = Wih[r0 * 6 + k]; wx[k].y = Wih[r1 * 6 + k]; }
    bias2.x = bih[r0] + bhh[r0];
    bias2.y = bih[r1] + bhh[r1];
    #pragma unroll
    for (int j = 0; j < 4; ++j) {
        const int m = q ^ j;
        const int u0 = 2 * m, u1 = 2 * m + 1;
        if (u0 < 6) { wh[2*j].x = Whh[r0*6 + u0]; wh[2*j].y = Whh[r1*6 + u0]; }
        else        { wh[2*j].x = 0.0f;           wh[2*j].y = 0.0f; }
        if (u1 < 6) { wh[2*j+1].x = Whh[r0*6 + u1]; wh[2*j+1].y = Whh[r1*6 + u1]; }
        else        { wh[2*j+1].x = 0.0f;           wh[2*j+1].y = 0.0f; }
    }

    // activation params: x-half = i (sigmoid) or g (tanh); y-half always sigmoid
    f32x2 mpk; mpk.x = p ? 1.0f : 0.5f; mpk.y = 0.5f;   // also the post-scale A
    f32x2 Cpk; Cpk.x = p ? 0.0f : 0.5f; Cpk.y = 0.5f;

    // packed rational constants
    f32x2 Ka13; Ka13.x = CA13; Ka13.y = CA13;
    f32x2 Ka11; Ka11.x = CA11; Ka11.y = CA11;
    f32x2 Ka9;  Ka9.x  = CA9;  Ka9.y  = CA9;
    f32x2 Ka7;  Ka7.x  = CA7;  Ka7.y  = CA7;
    f32x2 Ka5;  Ka5.x  = CA5;  Ka5.y  = CA5;
    f32x2 Ka3;  Ka3.x  = CA3;  Ka3.y  = CA3;
    f32x2 Ka1;  Ka1.x  = CA1;  Ka1.y  = CA1;
    f32x2 Kb6;  Kb6.x  = CB6;  Kb6.y  = CB6;
    f32x2 Kb4;  Kb4.x  = CB4;  Kb4.y  = CB4;
    f32x2 Kb2;  Kb2.x  = CB2;  Kb2.y  = CB2;
    f32x2 Kb0;  Kb0.x  = CB0;  Kb0.y  = CB0;

    // --- cooperative fill machinery: 768 f32x2 per chunk = 256 thr x 3 ---
    const float* fg[3];
    int fw[3];
    #pragma unroll
    for (int k = 0; k < 3; ++k) {
        const int j   = tid + k * 256;
        const int blf = j / 48;
        const int jj  = j - blf * 48;
        const int st  = jj / 3;
        const int off = 2 * (jj - st * 3);
        fg[k] = x + ((size_t)(blockIdx.x * 16 + blf) * T_STEPS + st) * 6 + off;
        fw[k] = (st * 16 + blf) * 8 + off;
        // fill chunk 0 into buffer 0
        *(f32x2*)&lds[fw[k]] = *(const f32x2*)fg[k];
    }
    __syncthreads();

    int addr = bl * 8;   // float index: current buffer base for this batch row

    // preload x(0), x(1) into slots A,B
    float4 s4A = *(const float4*)&lds[addr + 0];
    f32x2  s2A = *(const f32x2*)&lds[addr + 4];
    float4 s4B = *(const float4*)&lds[addr + 128];
    f32x2  s2B = *(const f32x2*)&lds[addr + 132];

    // x-part for step 0
    f32x2 axA = bias2, axB;
    {
        f32x2 xa, xb; xa.x = s4A.x; xa.y = s4A.y; xb.x = s4A.z; xb.y = s4A.w;
        pk_fma_lo(axA, wx[0], xa); pk_fma_hi(axA, wx[1], xa);
        pk_fma_lo(axA, wx[2], xb); pk_fma_hi(axA, wx[3], xb);
        pk_fma_lo(axA, wx[4], s2A); pk_fma_hi(axA, wx[5], s2A);
    }

    float c = 0.0f, h = 0.0f;

    auto STEP = [&](f32x2& AXC, f32x2& AXN, const float4 RS4, const f32x2 RS2,
                    float4& WS4, f32x2& WS2, int rdaddr) {
        // issue ds_read for x(t+2) (consumed next step; ~2 steps of cover)
        WS4 = *(const float4*)&lds[rdaddr];
        WS2 = *(const f32x2*)&lds[rdaddr + 4];

        // h gather: all-VALU DPP, depth 2
        f32x2 P, P1, P2, P3;
        P.x  = dpp_mov<QP_BCAST0>(h);         P.y  = dpp_mov<QP_BCAST2>(h);
        P1.x = dpp_mov<ROW_HALF_MIRROR>(P.x); P1.y = dpp_mov<ROW_HALF_MIRROR>(P.y);
        P2.x = dpp_mov<ROW_ROR8>(P.x);        P2.y = dpp_mov<ROW_ROR8>(P.y);
        P3.x = dpp_mov<ROW_MIRROR>(P.x);      P3.y = dpp_mov<ROW_MIRROR>(P.y);

        // h-part: two parallel 4-deep packed chains
        f32x2 acc = AXC, acc2; acc2.x = 0.0f; acc2.y = 0.0f;
        pk_fma_lo(acc, wh[0], P);  pk_fma_hi(acc2, wh[1], P);
        pk_fma_lo(acc, wh[2], P1); pk_fma_hi(acc2, wh[3], P1);
        pk_fma_lo(acc, wh[4], P2); pk_fma_hi(acc2, wh[5], P2);
        pk_fma_lo(acc, wh[6], P3); pk_fma_hi(acc2, wh[7], P3);

        // x-part for step t+1 (off-chain)
        {
            f32x2 xa, xb; xa.x = RS4.x; xa.y = RS4.y; xb.x = RS4.z; xb.y = RS4.w;
            AXN = bias2;
            pk_fma_lo(AXN, wx[0], xa); pk_fma_hi(AXN, wx[1], xa);
            pk_fma_lo(AXN, wx[2], xb); pk_fma_hi(AXN, wx[3], xb);
            pk_fma_lo(AXN, wx[4], RS2); pk_fma_hi(AXN, wx[5], RS2);
        }

        pk_add(acc, acc2);

        // packed rational activation: e = A*tanh(clamp(m*acc)) + C
        f32x2 u = pk_mul_e(mpk, acc);
        u.x = med3f(u.x, -TCL, TCL);
        u.y = med3f(u.y, -TCL, TCL);
        const f32x2 z = pk_mul_e(u, u);
        f32x2 Pv = pk_fma_e(z, Ka13, Ka11);
        Pv = pk_fma_e(z, Pv, Ka9); Pv = pk_fma_e(z, Pv, Ka7);
        Pv = pk_fma_e(z, Pv, Ka5); Pv = pk_fma_e(z, Pv, Ka3);
        Pv = pk_fma_e(z, Pv, Ka1);
        f32x2 Qv = pk_fma_e(z, Kb6, Kb4);
        Qv = pk_fma_e(z, Qv, Kb2); Qv = pk_fma_e(z, Qv, Kb0);
        const f32x2 au = pk_mul_e(mpk, u);
        const f32x2 nm = pk_mul_e(au, Pv);
        const float e0 = fmaf(nm.x, rcp_hw(Qv.x), Cpk.x);   // i or g
        const float e1 = fmaf(nm.y, rcp_hw(Qv.y), Cpk.y);   // f or o

        // pair exchange (lane^1)
        const float pa = dpp_mov<QP_SWAP1>(e0);
        const float pb = dpp_mov<QP_SWAP1>(e1);
        const float fv = p ? pb : e1;
        c = fmaf(fv, c, e0 * pa);
        const float th = tanh_rat(c);
        const float ov = p ? e1 : pb;
        h = ov * th;
    };

    for (int ck = 0; ck < NCHUNK; ++ck) {
        const int nb = addr ^ 2048;
        // issue fill loads for chunk ck+1 early (T14: issue-early / write-late)
        f32x2 st0, st1, st2;
        if (ck < NCHUNK - 1) {
            st0 = *(const f32x2*)(fg[0] + (ck + 1) * (CHUNK * 6));
            st1 = *(const f32x2*)(fg[1] + (ck + 1) * (CHUNK * 6));
            st2 = *(const f32x2*)(fg[2] + (ck + 1) * (CHUNK * 6));
        }
        STEP(axA, axB, s4B, s2B, s4A, s2A, addr + 2 * 128);   // ls=0
        STEP(axB, axA, s4A, s2A, s4B, s2B, addr + 3 * 128);   // ls=1
        STEP(axA, axB, s4B, s2B, s4A, s2A, addr + 4 * 128);   // ls=2
        STEP(axB, axA, s4A, s2A, s4B, s2B, addr + 5 * 128);   // ls=3
        STEP(axA, axB, s4B, s2B, s4A, s2A, addr + 6 * 128);   // ls=4
        STEP(axB, axA, s4A, s2A, s4B, s2B, addr + 7 * 128);   // ls=5
        STEP(axA, axB, s4B, s2B, s4A, s2A, addr + 8 * 128);   // ls=6
        STEP(axB, axA, s4A, s2A, s4B, s2B, addr + 9 * 128);   // ls=7
        STEP(axA, axB, s4B, s2B, s4A, s2A, addr + 10 * 128);  // ls=8
        STEP(axB, axA, s4A, s2A, s4B, s2B, addr + 11 * 128);  // ls=9
        STEP(axA, axB, s4B, s2B, s4A, s2A, addr + 12 * 128);  // ls=10
        STEP(axB, axA, s4A, s2A, s4B, s2B, addr + 13 * 128);  // ls=11
        STEP(axA, axB, s4B, s2B, s4A, s2A, addr + 14 * 128);  // ls=12
        STEP(axB, axA, s4A, s2A, s4B, s2B, addr + 15 * 128);  // ls=13
        if (ck < NCHUNK - 1) {
            *(f32x2*)&lds[fw[0] + (nb & 2048)] = st0;
            *(f32x2*)&lds[fw[1] + (nb & 2048)] = st1;
            *(f32x2*)&lds[fw[2] + (nb & 2048)] = st2;
        }
        __syncthreads();
        STEP(axA, axB, s4B, s2B, s4A, s2A, nb + 0 * 128);     // ls=14
        STEP(axB, axA, s4A, s2A, s4B, s2B, nb + 1 * 128);     // ls=15
        addr = nb;
    }

    // --- head: gather h0..h5, 6->4->2->softmax, store from s==0 ---
    float hf[6];
    hf[0] = swz16<0>(h); hf[1] = swz16<1>(h); hf[2] = swz16<2>(h);
    hf[3] = swz16<3>(h); hf[4] = swz16<4>(h); hf[5] = swz16<5>(h);

    float o1[4];
    #pragma unroll
    for (int j = 0; j < 4; ++j) {
        float a = b1v[j];
        #pragma unroll
        for (int k = 0; k < 6; ++k) a = fmaf(W1[j * 6 + k], hf[k], a);
        o1[j] = a;
    }
    float o2[2];
    #pragma unroll
    for (int m = 0; m < 2; ++m) {
        float a = b2v[m];
        #pragma unroll
        for (int j = 0; j < 4; ++j) a = fmaf(W2[m * 4 + j], o1[j], a);
        o2[m] = a;
    }
    const float mx  = fmaxf(o2[0], o2[1]);
    const float e0s = exp2_hw((o2[0] - mx) * 1.4426950408889634f);
    const float e1s = exp2_hw((o2[1] - mx) * 1.4426950408889634f);
    const float sc  = rcp_hw(e0s + e1s);

    if (s == 0) {
        ((float2*)out)[b] = make_float2(e0s * sc, e1s * sc);
    }
}

extern "C" void kernel_launch(void* const* d_in, const int* in_sizes, int n_in,
                              void* d_out, int out_size, void* d_ws, size_t ws_size,
                              hipStream_t stream) {
    const float* x   = (const float*)d_in[0];
    const float* Wih = (const float*)d_in[1];
    const float* Whh = (const float*)d_in[2];
    const float* bih = (const float*)d_in[3];
    const float* bhh = (const float*)d_in[4];
    const float* W1  = (const float*)d_in[5];
    const float* b1v = (const float*)d_in[6];
    const float* W2  = (const float*)d_in[7];
    const float* b2v = (const float*)d_in[8];
    float* out = (float*)d_out;

    // 16 lanes/batch, 4 batch/wave, 4 waves/block -> 16 batch/block -> 512 blocks
    // = 2048 waves = 2 waves/SIMD.
    const int blocks = BATCH / 16;
    lstm_r4_kernel<<<blocks, 256, 0, stream>>>(x, Wih, Whh, bih, bhh, W1, b1v, W2, b2v, out);
}

// Round 6
// 110.940 us; speedup vs baseline: 1.3374x; 1.3374x over previous
//
#include <hip/hip_runtime.h>

#define T_STEPS 512
#define BATCH   8192
#define CHUNK   16
#define NCHUNK  (T_STEPS / CHUNK)   // 32
#define ROWF    132                  // padded floats per step-row (16 batches x 8 + 4 pad)
#define BUFF    (CHUNK * ROWF)       // 2112 floats per buffer

typedef float f32x2 __attribute__((ext_vector_type(2)));

__device__ __forceinline__ float rcp_hw(float v)  { return __builtin_amdgcn_rcpf(v); }
__device__ __forceinline__ float exp2_hw(float v) { return __builtin_amdgcn_exp2f(v); }

// DPP cross-lane move (VALU pipe). CTRL compile-time.
template<int CTRL>
__device__ __forceinline__ float dpp_mov(float v) {
    return __int_as_float(__builtin_amdgcn_mov_dpp(__float_as_int(v), CTRL, 0xF, 0xF, true));
}
#define QP_BCAST0 0x00   // quad_perm [0,0,0,0]
#define QP_BCAST2 0xAA   // quad_perm [2,2,2,2]
#define QP_SWAP1  0xB1   // quad_perm [1,0,3,2]  (lane^1)
#define ROW_HALF_MIRROR 0x141  // lane^7  -> quad^1 (quad-uniform data)
#define ROW_ROR8        0x128  // lane^8  -> quad^2
#define ROW_MIRROR      0x140  // lane^15 -> quad^3

// one-time head gather: broadcast lane 2K of each 16-lane group
template<int K>
__device__ __forceinline__ float swz16(float v) {
    return __int_as_float(__builtin_amdgcn_ds_swizzle(__float_as_int(v), ((2*K) << 5) | 0x10));
}

// packed FMA with broadcast of b.lo / b.hi (verified R2-R4)
__device__ __forceinline__ void pk_fma_lo(f32x2& d, f32x2 a, f32x2 b) {
    asm("v_pk_fma_f32 %0, %1, %2, %0 op_sel:[0,0,0] op_sel_hi:[1,0,1]" : "+v"(d) : "v"(a), "v"(b));
}
__device__ __forceinline__ void pk_fma_hi(f32x2& d, f32x2 a, f32x2 b) {
    asm("v_pk_fma_f32 %0, %1, %2, %0 op_sel:[0,1,0] op_sel_hi:[1,1,1]" : "+v"(d) : "v"(a), "v"(b));
}
__device__ __forceinline__ void pk_add(f32x2& d, f32x2 a) {
    asm("v_pk_add_f32 %0, %0, %1" : "+v"(d) : "v"(a));
}

#define L2E  1.4426950408889634f

__global__ __launch_bounds__(256) void lstm_r5_kernel(
    const float* __restrict__ x,   const float* __restrict__ Wih,
    const float* __restrict__ Whh, const float* __restrict__ bih,
    const float* __restrict__ bhh, const float* __restrict__ W1,
    const float* __restrict__ b1v, const float* __restrict__ W2,
    const float* __restrict__ b2v, float* __restrict__ out)
{
    __shared__ float lds[2 * BUFF];

    const int tid  = threadIdx.x;
    const int lane = tid & 63;
    const int s    = lane & 15;        // slot within 16-lane batch group
    const int p    = s & 1;            // 0: gates {i,f}, 1: gates {g,o}
    const int pi   = s >> 1;           // pair index 0..7
    const int q    = (s >> 2) & 3;     // quad within group
    const int d    = (pi < 6) ? pi : pi - 2;
    const int bl   = (tid >> 6) * 4 + (lane >> 4);  // block-local batch 0..15
    const int b    = blockIdx.x * 16 + bl;

    const int r0 = (p ? 12 : 0) + d;   // i or g
    const int r1 = (p ? 18 : 6) + d;   // f or o

    f32x2 wx[6], wh[8], bias2;
    #pragma unroll
    for (int k = 0; k < 6; ++k) { wx[k].x = Wih[r0 * 6 + k]; wx[k].y = Wih[r1 * 6 + k]; }
    bias2.x = bih[r0] + bhh[r0];
    bias2.y = bih[r1] + bhh[r1];
    #pragma unroll
    for (int j = 0; j < 4; ++j) {
        const int m = q ^ j;
        const int u0 = 2 * m, u1 = 2 * m + 1;
        if (u0 < 6) { wh[2*j].x = Whh[r0*6 + u0]; wh[2*j].y = Whh[r1*6 + u0]; }
        else        { wh[2*j].x = 0.0f;           wh[2*j].y = 0.0f; }
        if (u1 < 6) { wh[2*j+1].x = Whh[r0*6 + u1]; wh[2*j+1].y = Whh[r1*6 + u1]; }
        else        { wh[2*j+1].x = 0.0f;           wh[2*j+1].y = 0.0f; }
    }

    // gate-0 activation consts: sigmoid (i, p=0) or tanh (g, p=1)
    const float em0 = p ? -2.0f * L2E : -L2E;
    const float am0 = p ? 2.0f : 1.0f;
    const float cm0 = p ? -1.0f : 0.0f;

    // --- cooperative fill: 768 f32x2 per chunk = 256 thr x 3, padded rows ---
    const float* fg[3];
    int fw[3];
    #pragma unroll
    for (int k = 0; k < 3; ++k) {
        const int j   = tid + k * 256;
        const int blf = j / 48;
        const int jj  = j - blf * 48;
        const int st  = jj / 3;
        const int off = 2 * (jj - st * 3);
        fg[k] = x + ((size_t)(blockIdx.x * 16 + blf) * T_STEPS + st) * 6 + off;
        fw[k] = st * ROWF + blf * 8 + off;
        *(f32x2*)&lds[fw[k]] = *(const f32x2*)fg[k];   // chunk 0 -> buffer 0
    }
    __syncthreads();

    int cur = 0;                 // current buffer base (floats)
    const int rb = bl * 8;       // this batch's offset within a step-row

    // preload x(0), x(1)
    float4 s4A = *(const float4*)&lds[cur + 0 * ROWF + rb];
    f32x2  s2A = *(const f32x2*)&lds[cur + 0 * ROWF + rb + 4];
    float4 s4B = *(const float4*)&lds[cur + 1 * ROWF + rb];
    f32x2  s2B = *(const f32x2*)&lds[cur + 1 * ROWF + rb + 4];

    // x-part for step 0
    f32x2 axA = bias2, axB;
    {
        f32x2 xa, xb; xa.x = s4A.x; xa.y = s4A.y; xb.x = s4A.z; xb.y = s4A.w;
        pk_fma_lo(axA, wx[0], xa); pk_fma_hi(axA, wx[1], xa);
        pk_fma_lo(axA, wx[2], xb); pk_fma_hi(axA, wx[3], xb);
        pk_fma_lo(axA, wx[4], s2A); pk_fma_hi(axA, wx[5], s2A);
    }

    float c = 0.0f, h = 0.0f;

    auto STEP = [&](f32x2& AXC, f32x2& AXN, const float4 RS4, const f32x2 RS2,
                    float4& WS4, f32x2& WS2, int rdaddr) {
        // ds_read for x(t+2): consumed next step (1-step distance, ample cover)
        WS4 = *(const float4*)&lds[rdaddr];
        WS2 = *(const f32x2*)&lds[rdaddr + 4];

        // h gather: all-VALU DPP, depth 2
        f32x2 P, P1, P2, P3;
        P.x  = dpp_mov<QP_BCAST0>(h);         P.y  = dpp_mov<QP_BCAST2>(h);
        P1.x = dpp_mov<ROW_HALF_MIRROR>(P.x); P1.y = dpp_mov<ROW_HALF_MIRROR>(P.y);
        P2.x = dpp_mov<ROW_ROR8>(P.x);        P2.y = dpp_mov<ROW_ROR8>(P.y);
        P3.x = dpp_mov<ROW_MIRROR>(P.x);      P3.y = dpp_mov<ROW_MIRROR>(P.y);

        // h-part: two parallel 4-deep packed chains
        f32x2 acc = AXC, acc2; acc2.x = 0.0f; acc2.y = 0.0f;
        pk_fma_lo(acc, wh[0], P);  pk_fma_hi(acc2, wh[1], P);
        pk_fma_lo(acc, wh[2], P1); pk_fma_hi(acc2, wh[3], P1);
        pk_fma_lo(acc, wh[4], P2); pk_fma_hi(acc2, wh[5], P2);
        pk_fma_lo(acc, wh[6], P3); pk_fma_hi(acc2, wh[7], P3);

        // x-part for step t+1 (off-chain)
        {
            f32x2 xa, xb; xa.x = RS4.x; xa.y = RS4.y; xb.x = RS4.z; xb.y = RS4.w;
            AXN = bias2;
            pk_fma_lo(AXN, wx[0], xa); pk_fma_hi(AXN, wx[1], xa);
            pk_fma_lo(AXN, wx[2], xb); pk_fma_hi(AXN, wx[3], xb);
            pk_fma_lo(AXN, wx[4], RS2); pk_fma_hi(AXN, wx[5], RS2);
        }

        pk_add(acc, acc2);

        // cheap activations: sigmoid/tanh via exp2 + rcp (e0, e1 independent)
        const float e0 = fmaf(am0, rcp_hw(1.0f + exp2_hw(acc.x * em0)), cm0); // i or g
        const float e1 = rcp_hw(1.0f + exp2_hw(acc.y * -L2E));                // f or o

        // pair exchange (lane^1)
        const float pa = dpp_mov<QP_SWAP1>(e0);
        const float pb = dpp_mov<QP_SWAP1>(e1);
        const float fv = p ? pb : e1;   // forget gate on both halves
        const float ov = p ? e1 : pb;   // output gate on both halves
        c = fmaf(fv, c, e0 * pa);       // i*g == e0*pa on both halves
        // h = ov * tanh(c) = fma(2*ov, rcp(1+exp2(-2c*log2e)), -ov)
        const float r  = rcp_hw(1.0f + exp2_hw(c * (-2.0f * L2E)));
        h = fmaf(ov + ov, r, -ov);
    };

    for (int ck = 0; ck < NCHUNK; ++ck) {
        const int nxt = BUFF - cur;
        // issue fill loads for chunk ck+1 early (write-late after the main steps)
        f32x2 st0, st1, st2;
        if (ck < NCHUNK - 1) {
            st0 = *(const f32x2*)(fg[0] + (ck + 1) * (CHUNK * 6));
            st1 = *(const f32x2*)(fg[1] + (ck + 1) * (CHUNK * 6));
            st2 = *(const f32x2*)(fg[2] + (ck + 1) * (CHUNK * 6));
        }
        STEP(axA, axB, s4B, s2B, s4A, s2A, cur +  2 * ROWF + rb);  // ls=0
        STEP(axB, axA, s4A, s2A, s4B, s2B, cur +  3 * ROWF + rb);  // ls=1
        STEP(axA, axB, s4B, s2B, s4A, s2A, cur +  4 * ROWF + rb);  // ls=2
        STEP(axB, axA, s4A, s2A, s4B, s2B, cur +  5 * ROWF + rb);  // ls=3
        STEP(axA, axB, s4B, s2B, s4A, s2A, cur +  6 * ROWF + rb);  // ls=4
        STEP(axB, axA, s4A, s2A, s4B, s2B, cur +  7 * ROWF + rb);  // ls=5
        STEP(axA, axB, s4B, s2B, s4A, s2A, cur +  8 * ROWF + rb);  // ls=6
        STEP(axB, axA, s4A, s2A, s4B, s2B, cur +  9 * ROWF + rb);  // ls=7
        STEP(axA, axB, s4B, s2B, s4A, s2A, cur + 10 * ROWF + rb);  // ls=8
        STEP(axB, axA, s4A, s2A, s4B, s2B, cur + 11 * ROWF + rb);  // ls=9
        STEP(axA, axB, s4B, s2B, s4A, s2A, cur + 12 * ROWF + rb);  // ls=10
        STEP(axB, axA, s4A, s2A, s4B, s2B, cur + 13 * ROWF + rb);  // ls=11
        STEP(axA, axB, s4B, s2B, s4A, s2A, cur + 14 * ROWF + rb);  // ls=12
        STEP(axB, axA, s4A, s2A, s4B, s2B, cur + 15 * ROWF + rb);  // ls=13
        if (ck < NCHUNK - 1) {
            *(f32x2*)&lds[fw[0] + nxt] = st0;
            *(f32x2*)&lds[fw[1] + nxt] = st1;
            *(f32x2*)&lds[fw[2] + nxt] = st2;
        }
        __syncthreads();
        STEP(axA, axB, s4B, s2B, s4A, s2A, nxt + 0 * ROWF + rb);   // ls=14
        STEP(axB, axA, s4A, s2A, s4B, s2B, nxt + 1 * ROWF + rb);   // ls=15
        cur = nxt;
    }

    // --- head: gather h0..h5, 6->4->2->softmax, store from s==0 ---
    float hf[6];
    hf[0] = swz16<0>(h); hf[1] = swz16<1>(h); hf[2] = swz16<2>(h);
    hf[3] = swz16<3>(h); hf[4] = swz16<4>(h); hf[5] = swz16<5>(h);

    float o1[4];
    #pragma unroll
    for (int j = 0; j < 4; ++j) {
        float a = b1v[j];
        #pragma unroll
        for (int k = 0; k < 6; ++k) a = fmaf(W1[j * 6 + k], hf[k], a);
        o1[j] = a;
    }
    float o2[2];
    #pragma unroll
    for (int m = 0; m < 2; ++m) {
        float a = b2v[m];
        #pragma unroll
        for (int j = 0; j < 4; ++j) a = fmaf(W2[m * 4 + j], o1[j], a);
        o2[m] = a;
    }
    const float mx  = fmaxf(o2[0], o2[1]);
    const float e0s = exp2_hw((o2[0] - mx) * L2E);
    const float e1s = exp2_hw((o2[1] - mx) * L2E);
    const float sc  = rcp_hw(e0s + e1s);

    if (s == 0) {
        ((float2*)out)[b] = make_float2(e0s * sc, e1s * sc);
    }
}

extern "C" void kernel_launch(void* const* d_in, const int* in_sizes, int n_in,
                              void* d_out, int out_size, void* d_ws, size_t ws_size,
                              hipStream_t stream) {
    const float* x   = (const float*)d_in[0];
    const float* Wih = (const float*)d_in[1];
    const float* Whh = (const float*)d_in[2];
    const float* bih = (const float*)d_in[3];
    const float* bhh = (const float*)d_in[4];
    const float* W1  = (const float*)d_in[5];
    const float* b1v = (const float*)d_in[6];
    const float* W2  = (const float*)d_in[7];
    const float* b2v = (const float*)d_in[8];
    float* out = (float*)d_out;

    // 16 lanes/batch, 4 batch/wave, 4 waves/block -> 16 batch/block -> 512 blocks
    // = 2048 waves = 2 waves/SIMD.
    const int blocks = BATCH / 16;
    lstm_r5_kernel<<<blocks, 256, 0, stream>>>(x, Wih, Whh, bih, bhh, W1, b1v, W2, b2v, out);
}

// Round 7
// 89.031 us; speedup vs baseline: 1.6665x; 1.2461x over previous
//
#include <hip/hip_runtime.h>

#define T_STEPS 512
#define BATCH   8192
#define CHUNK   16
#define NCHUNK  (T_STEPS / CHUNK)   // 32
#define ROWSZ   256                  // floats per step-row (32 batches x 8)
#define BUFF    (CHUNK * ROWSZ)      // 4096 floats per buffer

typedef float f32x2 __attribute__((ext_vector_type(2)));

#define L2E 1.4426950408889634f

__device__ __forceinline__ float rcp_hw(float v)  { return __builtin_amdgcn_rcpf(v); }
__device__ __forceinline__ float exp2_hw(float v) { return __builtin_amdgcn_exp2f(v); }

// DPP cross-lane move (VALU pipe). CTRL compile-time.
template<int CTRL>
__device__ __forceinline__ float dpp_mov(float v) {
    return __int_as_float(__builtin_amdgcn_mov_dpp(__float_as_int(v), CTRL, 0xF, 0xF, true));
}
#define QP_X1    0xB1   // quad_perm [1,0,3,2] : lane^1
#define QP_X2    0x4E   // quad_perm [2,3,0,1] : lane^2
#define ROW_ROR8 0x128  // row_ror:8          : lane^8 (within 16-lane row)

// packed FMA/MUL with broadcast of B.lo / B.hi (op_sel semantics verified R2-R5)
__device__ __forceinline__ void pk_fma_lo(f32x2& d, f32x2 a, f32x2 b) {
    asm("v_pk_fma_f32 %0, %1, %2, %0 op_sel:[0,0,0] op_sel_hi:[1,0,1]" : "+v"(d) : "v"(a), "v"(b));
}
__device__ __forceinline__ void pk_fma_hi(f32x2& d, f32x2 a, f32x2 b) {
    asm("v_pk_fma_f32 %0, %1, %2, %0 op_sel:[0,1,0] op_sel_hi:[1,1,1]" : "+v"(d) : "v"(a), "v"(b));
}
__device__ __forceinline__ f32x2 pk_mul_lo(f32x2 a, f32x2 b) {
    f32x2 d; asm("v_pk_mul_f32 %0, %1, %2 op_sel:[0,0] op_sel_hi:[1,0]" : "=v"(d) : "v"(a), "v"(b)); return d;
}
__device__ __forceinline__ void pk_add(f32x2& d, f32x2 a) {
    asm("v_pk_add_f32 %0, %0, %1" : "+v"(d) : "v"(a));
}

__global__ __launch_bounds__(256) void lstm_r6_kernel(
    const float* __restrict__ x,   const float* __restrict__ Wih,
    const float* __restrict__ Whh, const float* __restrict__ bih,
    const float* __restrict__ bhh, const float* __restrict__ W1,
    const float* __restrict__ b1v, const float* __restrict__ W2,
    const float* __restrict__ b2v, float* __restrict__ out)
{
    __shared__ float lds[2 * BUFF];   // 32 KB

    const int tid  = threadIdx.x;
    const int lane = tid & 63;
    const int r    = lane & 15;                    // row-local lane
    const int u    = (r & 3) | ((r >> 1) & 4);     // slot 0..7 in XOR group {^1,^2,^8}
    const int d    = (u < 6) ? u : u - 2;          // unit owned (slots 6,7 dup 4,5)
    const int grp  = ((lane >> 4) << 1) | ((lane >> 2) & 1);  // 8 groups/wave
    const int bl   = ((tid >> 6) << 3) | grp;      // block-local batch 0..31
    const int b    = blockIdx.x * 32 + bl;

    const int ri = d, rf = 6 + d, rg = 12 + d, ro = 18 + d;
    const float SIF = -L2E;          // sigmoid pre-scale (i, f, o rows)
    const float SGG = -2.0f * L2E;   // tanh pre-scale (g row)

    // ---- weights (pre-scaled so exp2 consumes preacts directly) ----
    f32x2 wxIF[6], wxGO[6], whIF[8], whGO[8], bIF, bGO;
    #pragma unroll
    for (int k = 0; k < 6; ++k) {
        wxIF[k].x = SIF * Wih[ri * 6 + k]; wxIF[k].y = SIF * Wih[rf * 6 + k];
        wxGO[k].x = SGG * Wih[rg * 6 + k]; wxGO[k].y = SIF * Wih[ro * 6 + k];
    }
    bIF.x = SIF * (bih[ri] + bhh[ri]); bIF.y = SIF * (bih[rf] + bhh[rf]);
    bGO.x = SGG * (bih[rg] + bhh[rg]); bGO.y = SIF * (bih[ro] + bhh[ro]);
    #pragma unroll
    for (int j = 0; j < 8; ++j) {
        const int v = u ^ j;           // arrival j carries h of slot v
        if (v < 6) {
            whIF[j].x = SIF * Whh[ri * 6 + v]; whIF[j].y = SIF * Whh[rf * 6 + v];
            whGO[j].x = SGG * Whh[rg * 6 + v]; whGO[j].y = SIF * Whh[ro * 6 + v];
        } else {                        // dup-slot arrival: zero weight
            whIF[j].x = 0.0f; whIF[j].y = 0.0f;
            whGO[j].x = 0.0f; whGO[j].y = 0.0f;
        }
    }

    // ---- cooperative x fill: 1536 f32x2/chunk = 256 thr x 6 ----
    const float* fg[6]; int fw[6];
    #pragma unroll
    for (int k = 0; k < 6; ++k) {
        const int j   = tid + k * 256;
        const int st  = j / 96;
        const int rem = j - st * 96;
        const int b2  = rem / 3;
        const int off = (rem - b2 * 3) * 2;
        fg[k] = x + ((size_t)(blockIdx.x * 32 + b2) * T_STEPS + st) * 6 + off;
        fw[k] = (st * 32 + b2) * 8 + off;
        *(f32x2*)&lds[fw[k]] = *(const f32x2*)fg[k];   // chunk 0 -> buffer 0
    }
    __syncthreads();

    int cur = 0;
    const int rb = bl * 8;

    // preload x(0), x(1); all 8 lanes of a group read the same address (broadcast)
    float4 s4A = *(const float4*)&lds[cur + rb];
    f32x2  s2A = *(const f32x2*)&lds[cur + rb + 4];
    float4 s4B = *(const float4*)&lds[cur + ROWSZ + rb];
    f32x2  s2B = *(const f32x2*)&lds[cur + ROWSZ + rb + 4];

    // x-part for step 0
    f32x2 axIFA = bIF, axGOA = bGO, axIFB, axGOB;
    {
        const f32x2* xp = (const f32x2*)&s4A;
        pk_fma_lo(axIFA, wxIF[0], xp[0]); pk_fma_hi(axIFA, wxIF[1], xp[0]);
        pk_fma_lo(axIFA, wxIF[2], xp[1]); pk_fma_hi(axIFA, wxIF[3], xp[1]);
        pk_fma_lo(axIFA, wxIF[4], s2A);   pk_fma_hi(axIFA, wxIF[5], s2A);
        pk_fma_lo(axGOA, wxGO[0], xp[0]); pk_fma_hi(axGOA, wxGO[1], xp[0]);
        pk_fma_lo(axGOA, wxGO[2], xp[1]); pk_fma_hi(axGOA, wxGO[3], xp[1]);
        pk_fma_lo(axGOA, wxGO[4], s2A);   pk_fma_hi(axGOA, wxGO[5], s2A);
    }

    float c = 0.0f, h = 0.0f;

    auto STEP = [&](f32x2& axIFc, f32x2& axGOc, f32x2& axIFn, f32x2& axGOn,
                    const float4 RS4, const f32x2 RS2,
                    float4& WS4, f32x2& WS2, int rdaddr) {
        // ds_read for x(t+2), consumed next step
        WS4 = *(const float4*)&lds[rdaddr];
        WS2 = *(const f32x2*)&lds[rdaddr + 4];

        // h all-gather: 7 chained DPP movs (slots u^1..u^7), pure VALU
        f32x2 A0, A1, A2, A3;
        A0.x = h;
        A0.y = dpp_mov<QP_X1>(h);
        A1.x = dpp_mov<QP_X2>(h);     A1.y = dpp_mov<QP_X2>(A0.y);
        A2.x = dpp_mov<ROW_ROR8>(h);  A2.y = dpp_mov<ROW_ROR8>(A0.y);
        A3.x = dpp_mov<ROW_ROR8>(A1.x); A3.y = dpp_mov<ROW_ROR8>(A1.y);

        // h-part: 4 parallel packed chains, then combine
        f32x2 aIF = axIFc, aGO = axGOc;
        pk_fma_lo(aIF, whIF[0], A0); pk_fma_hi(aIF, whIF[1], A0);
        pk_fma_lo(aIF, whIF[2], A1); pk_fma_hi(aIF, whIF[3], A1);
        f32x2 aIF2 = pk_mul_lo(whIF[4], A2);
        pk_fma_hi(aIF2, whIF[5], A2);
        pk_fma_lo(aIF2, whIF[6], A3); pk_fma_hi(aIF2, whIF[7], A3);
        pk_fma_lo(aGO, whGO[0], A0); pk_fma_hi(aGO, whGO[1], A0);
        pk_fma_lo(aGO, whGO[2], A1); pk_fma_hi(aGO, whGO[3], A1);
        f32x2 aGO2 = pk_mul_lo(whGO[4], A2);
        pk_fma_hi(aGO2, whGO[5], A2);
        pk_fma_lo(aGO2, whGO[6], A3); pk_fma_hi(aGO2, whGO[7], A3);
        pk_add(aIF, aIF2);
        pk_add(aGO, aGO2);

        // x-part for step t+1 (independent filler for the act/tanh chains)
        {
            const f32x2* xp = (const f32x2*)&RS4;
            axIFn = bIF; axGOn = bGO;
            pk_fma_lo(axIFn, wxIF[0], xp[0]); pk_fma_hi(axIFn, wxIF[1], xp[0]);
            pk_fma_lo(axIFn, wxIF[2], xp[1]); pk_fma_hi(axIFn, wxIF[3], xp[1]);
            pk_fma_lo(axIFn, wxIF[4], RS2);   pk_fma_hi(axIFn, wxIF[5], RS2);
            pk_fma_lo(axGOn, wxGO[0], xp[0]); pk_fma_hi(axGOn, wxGO[1], xp[0]);
            pk_fma_lo(axGOn, wxGO[2], xp[1]); pk_fma_hi(axGOn, wxGO[3], xp[1]);
            pk_fma_lo(axGOn, wxGO[4], RS2);   pk_fma_hi(axGOn, wxGO[5], RS2);
        }

        // activations (preacts already scaled for exp2), all lane-local
        const float iv = rcp_hw(1.0f + exp2_hw(aIF.x));
        const float fv = rcp_hw(1.0f + exp2_hw(aIF.y));
        const float gv = fmaf(2.0f, rcp_hw(1.0f + exp2_hw(aGO.x)), -1.0f);
        const float ov = rcp_hw(1.0f + exp2_hw(aGO.y));
        c = fmaf(fv, c, iv * gv);
        const float tt = fmaf(2.0f, rcp_hw(1.0f + exp2_hw(c * SGG)), -1.0f);
        h = ov * tt;
    };

    for (int ck = 0; ck < NCHUNK; ++ck) {
        const int nxt = BUFF - cur;
        // issue fill loads for chunk ck+1 early; write late (T14 split)
        f32x2 st0, st1, st2, st3, st4, st5;
        if (ck < NCHUNK - 1) {
            const int adv = (ck + 1) * (CHUNK * 6);
            st0 = *(const f32x2*)(fg[0] + adv); st1 = *(const f32x2*)(fg[1] + adv);
            st2 = *(const f32x2*)(fg[2] + adv); st3 = *(const f32x2*)(fg[3] + adv);
            st4 = *(const f32x2*)(fg[4] + adv); st5 = *(const f32x2*)(fg[5] + adv);
        }
        STEP(axIFA, axGOA, axIFB, axGOB, s4B, s2B, s4A, s2A, cur +  2 * ROWSZ + rb); // ls=0
        STEP(axIFB, axGOB, axIFA, axGOA, s4A, s2A, s4B, s2B, cur +  3 * ROWSZ + rb); // ls=1
        STEP(axIFA, axGOA, axIFB, axGOB, s4B, s2B, s4A, s2A, cur +  4 * ROWSZ + rb); // ls=2
        STEP(axIFB, axGOB, axIFA, axGOA, s4A, s2A, s4B, s2B, cur +  5 * ROWSZ + rb); // ls=3
        STEP(axIFA, axGOA, axIFB, axGOB, s4B, s2B, s4A, s2A, cur +  6 * ROWSZ + rb); // ls=4
        STEP(axIFB, axGOB, axIFA, axGOA, s4A, s2A, s4B, s2B, cur +  7 * ROWSZ + rb); // ls=5
        STEP(axIFA, axGOA, axIFB, axGOB, s4B, s2B, s4A, s2A, cur +  8 * ROWSZ + rb); // ls=6
        STEP(axIFB, axGOB, axIFA, axGOA, s4A, s2A, s4B, s2B, cur +  9 * ROWSZ + rb); // ls=7
        STEP(axIFA, axGOA, axIFB, axGOB, s4B, s2B, s4A, s2A, cur + 10 * ROWSZ + rb); // ls=8
        STEP(axIFB, axGOB, axIFA, axGOA, s4A, s2A, s4B, s2B, cur + 11 * ROWSZ + rb); // ls=9
        STEP(axIFA, axGOA, axIFB, axGOB, s4B, s2B, s4A, s2A, cur + 12 * ROWSZ + rb); // ls=10
        STEP(axIFB, axGOB, axIFA, axGOA, s4A, s2A, s4B, s2B, cur + 13 * ROWSZ + rb); // ls=11
        STEP(axIFA, axGOA, axIFB, axGOB, s4B, s2B, s4A, s2A, cur + 14 * ROWSZ + rb); // ls=12
        STEP(axIFB, axGOB, axIFA, axGOA, s4A, s2A, s4B, s2B, cur + 15 * ROWSZ + rb); // ls=13
        if (ck < NCHUNK - 1) {
            *(f32x2*)&lds[fw[0] + nxt] = st0; *(f32x2*)&lds[fw[1] + nxt] = st1;
            *(f32x2*)&lds[fw[2] + nxt] = st2; *(f32x2*)&lds[fw[3] + nxt] = st3;
            *(f32x2*)&lds[fw[4] + nxt] = st4; *(f32x2*)&lds[fw[5] + nxt] = st5;
        }
        __syncthreads();
        STEP(axIFA, axGOA, axIFB, axGOB, s4B, s2B, s4A, s2A, nxt + 0 * ROWSZ + rb);  // ls=14
        STEP(axIFB, axGOB, axIFA, axGOA, s4A, s2A, s4B, s2B, nxt + 1 * ROWSZ + rb);  // ls=15
        cur = nxt;
    }

    // ---- head: final h all-gather (same 7 DPPs), 6->4->2->softmax ----
    f32x2 A0, A1, A2, A3;
    A0.x = h;
    A0.y = dpp_mov<QP_X1>(h);
    A1.x = dpp_mov<QP_X2>(h);       A1.y = dpp_mov<QP_X2>(A0.y);
    A2.x = dpp_mov<ROW_ROR8>(h);    A2.y = dpp_mov<ROW_ROR8>(A0.y);
    A3.x = dpp_mov<ROW_ROR8>(A1.x); A3.y = dpp_mov<ROW_ROR8>(A1.y);
    float arr[8] = {A0.x, A0.y, A1.x, A1.y, A2.x, A2.y, A3.x, A3.y};

    float o1[4];
    #pragma unroll
    for (int m = 0; m < 4; ++m) {
        float a = b1v[m];
        #pragma unroll
        for (int j = 0; j < 8; ++j) {
            const int v  = u ^ j;
            const int vi = (v < 6) ? v : 0;          // safe index
            const float w = (v < 6) ? W1[m * 6 + vi] : 0.0f;
            a = fmaf(w, arr[j], a);
        }
        o1[m] = a;
    }
    float o2[2];
    #pragma unroll
    for (int m = 0; m < 2; ++m) {
        float a = b2v[m];
        #pragma unroll
        for (int j = 0; j < 4; ++j) a = fmaf(W2[m * 4 + j], o1[j], a);
        o2[m] = a;
    }
    const float mx  = fmaxf(o2[0], o2[1]);
    const float e0s = exp2_hw((o2[0] - mx) * L2E);
    const float e1s = exp2_hw((o2[1] - mx) * L2E);
    const float sc  = rcp_hw(e0s + e1s);

    if (u == 0) {
        ((float2*)out)[b] = make_float2(e0s * sc, e1s * sc);
    }
}

extern "C" void kernel_launch(void* const* d_in, const int* in_sizes, int n_in,
                              void* d_out, int out_size, void* d_ws, size_t ws_size,
                              hipStream_t stream) {
    const float* x   = (const float*)d_in[0];
    const float* Wih = (const float*)d_in[1];
    const float* Whh = (const float*)d_in[2];
    const float* bih = (const float*)d_in[3];
    const float* bhh = (const float*)d_in[4];
    const float* W1  = (const float*)d_in[5];
    const float* b1v = (const float*)d_in[6];
    const float* W2  = (const float*)d_in[7];
    const float* b2v = (const float*)d_in[8];
    float* out = (float*)d_out;

    // 8-lane XOR groups, 8 batches/wave, 4 waves/block -> 32 batch/block
    // -> 256 blocks = 1024 waves = 1 wave/SIMD on 256 CUs.
    const int blocks = BATCH / 32;
    lstm_r6_kernel<<<blocks, 256, 0, stream>>>(x, Wih, Whh, bih, bhh, W1, b1v, W2, b2v, out);
}

// Round 9
// 85.836 us; speedup vs baseline: 1.7285x; 1.0372x over previous
//
#include <hip/hip_runtime.h>

#define T_STEPS 512
#define BATCH   8192
#define CHUNK   16
#define NCHUNK  (T_STEPS / CHUNK)   // 32
#define ROWD    128                  // dwords per step-row (32 batches x 4)
#define BUFD    (CHUNK * ROWD)       // 2048 dwords per buffer

typedef float f32x2 __attribute__((ext_vector_type(2)));

#define L2E 1.4426950408889634f

__device__ __forceinline__ float rcp_hw(float v)  { return __builtin_amdgcn_rcpf(v); }
__device__ __forceinline__ float exp2_hw(float v) { return __builtin_amdgcn_exp2f(v); }

// DPP cross-lane move (VALU pipe). CTRL compile-time.
template<int CTRL>
__device__ __forceinline__ unsigned dpp_movu(unsigned v) {
    return (unsigned)__builtin_amdgcn_mov_dpp((int)v, CTRL, 0xF, 0xF, true);
}
template<int CTRL>
__device__ __forceinline__ float dpp_movf(float v) {
    return __int_as_float(__builtin_amdgcn_mov_dpp(__float_as_int(v), CTRL, 0xF, 0xF, true));
}
#define QP_X1    0xB1   // quad_perm [1,0,3,2] : lane^1
#define QP_X2    0x4E   // quad_perm [2,3,0,1] : lane^2
#define ROW_ROR8 0x128  // row_ror:8          : lane^8 (== XOR8 in 16-lane row)

// pack two f32 into one dword of f16 pairs (RTZ)
__device__ __forceinline__ unsigned pack2(float a, float b) {
    auto t = __builtin_amdgcn_cvt_pkrtz(a, b);   // __fp16 ext_vector_type(2)
    return __builtin_bit_cast(unsigned int, t);
}
// acc += dot(f16pair w, f16pair v)  -- f32 accumulate
__device__ __forceinline__ void dot2(float& acc, unsigned w, unsigned v) {
    asm("v_dot2_f32_f16 %0, %1, %2, %0" : "+v"(acc) : "v"(w), "v"(v));
}

__global__ __launch_bounds__(256) void lstm_r7_kernel(
    const float* __restrict__ x,   const float* __restrict__ Wih,
    const float* __restrict__ Whh, const float* __restrict__ bih,
    const float* __restrict__ bhh, const float* __restrict__ W1,
    const float* __restrict__ b1v, const float* __restrict__ W2,
    const float* __restrict__ b2v, float* __restrict__ out)
{
    __shared__ unsigned lds[2 * BUFD];   // 16 KB, x as packed f16 pairs

    const int tid  = threadIdx.x;
    const int lane = tid & 63;
    const int r    = lane & 15;                    // row-local lane
    const int u    = (r & 3) | ((r >> 1) & 4);     // slot 0..7 in XOR group {^1,^2,^8}
    const int d    = (u < 6) ? u : u - 2;          // unit owned (slots 6,7 dup 4,5)
    const int grp  = ((lane >> 4) << 1) | ((lane >> 2) & 1);
    const int bl   = ((tid >> 6) << 3) | grp;      // block-local batch 0..31
    const int b    = blockIdx.x * 32 + bl;

    const int ri = d, rf = 6 + d, rg = 12 + d, ro = 18 + d;
    const float SIF = -L2E;          // sigmoid pre-scale (i,f,o)
    const float SGG = -2.0f * L2E;   // tanh pre-scale (g)

    // ---- packed f16 weights (pre-scaled so exp2 consumes preacts directly) ----
    unsigned wxi[3], wxf[3], wxg[3], wxo[3];
    #pragma unroll
    for (int k = 0; k < 3; ++k) {
        wxi[k] = pack2(SIF * Wih[ri*6 + 2*k], SIF * Wih[ri*6 + 2*k + 1]);
        wxf[k] = pack2(SIF * Wih[rf*6 + 2*k], SIF * Wih[rf*6 + 2*k + 1]);
        wxg[k] = pack2(SGG * Wih[rg*6 + 2*k], SGG * Wih[rg*6 + 2*k + 1]);
        wxo[k] = pack2(SIF * Wih[ro*6 + 2*k], SIF * Wih[ro*6 + 2*k + 1]);
    }
    unsigned whi[4], whf[4], whg[4], who[4];
    #pragma unroll
    for (int j = 0; j < 4; ++j) {
        const int v0 = u ^ (2*j), v1 = u ^ (2*j + 1);
        const float z = 0.0f;
        whi[j] = pack2(v0 < 6 ? SIF*Whh[ri*6 + v0] : z, v1 < 6 ? SIF*Whh[ri*6 + v1] : z);
        whf[j] = pack2(v0 < 6 ? SIF*Whh[rf*6 + v0] : z, v1 < 6 ? SIF*Whh[rf*6 + v1] : z);
        whg[j] = pack2(v0 < 6 ? SGG*Whh[rg*6 + v0] : z, v1 < 6 ? SGG*Whh[rg*6 + v1] : z);
        who[j] = pack2(v0 < 6 ? SIF*Whh[ro*6 + v0] : z, v1 < 6 ? SIF*Whh[ro*6 + v1] : z);
    }
    const float bi = SIF * (bih[ri] + bhh[ri]);
    const float bfv = SIF * (bih[rf] + bhh[rf]);
    const float bg = SGG * (bih[rg] + bhh[rg]);
    const float bo = SIF * (bih[ro] + bhh[ro]);

    // ---- cooperative x fill: 1536 pair-dwords/chunk = 256 thr x 6 ----
    const float* fg[6]; int fw[6];
    #pragma unroll
    for (int k = 0; k < 6; ++k) {
        const int j   = tid + k * 256;
        const int st  = j / 96;
        const int rem = j - st * 96;
        const int b2  = rem / 3;
        const int off = rem - b2 * 3;
        fg[k] = x + ((size_t)(blockIdx.x * 32 + b2) * T_STEPS + st) * 6 + off * 2;
        fw[k] = st * ROWD + b2 * 4 + off;
        f32x2 v = *(const f32x2*)fg[k];
        lds[fw[k]] = pack2(v.x, v.y);       // chunk 0 -> buffer 0
    }
    __syncthreads();

    int cur = 0;
    const int rb = bl * 4;

    // preload x(0), x(1) (all 8 lanes of a group read same address -> broadcast)
    unsigned sA0 = lds[rb],        sA1 = lds[rb + 1],        sA2 = lds[rb + 2];
    unsigned sB0 = lds[ROWD + rb], sB1 = lds[ROWD + rb + 1], sB2 = lds[ROWD + rb + 2];

    // x-part for step 0
    float axiA = bi, axfA = bfv, axgA = bg, axoA = bo;
    dot2(axiA, wxi[0], sA0); dot2(axiA, wxi[1], sA1); dot2(axiA, wxi[2], sA2);
    dot2(axfA, wxf[0], sA0); dot2(axfA, wxf[1], sA1); dot2(axfA, wxf[2], sA2);
    dot2(axgA, wxg[0], sA0); dot2(axgA, wxg[1], sA1); dot2(axgA, wxg[2], sA2);
    dot2(axoA, wxo[0], sA0); dot2(axoA, wxo[1], sA1); dot2(axoA, wxo[2], sA2);
    float axiB, axfB, axgB, axoB;

    float c = 0.0f, h = 0.0f;

    auto STEP = [&](float& AXI, float& AXF, float& AXG, float& AXO,
                    float& NXI, float& NXF, float& NXG, float& NXO,
                    unsigned RS0, unsigned RS1, unsigned RS2,
                    unsigned& WS0, unsigned& WS1, unsigned& WS2, int rdaddr) {
        // ds_read x(t+2), consumed next step (~1 step of latency cover)
        WS0 = lds[rdaddr]; WS1 = lds[rdaddr + 1]; WS2 = lds[rdaddr + 2];

        // h gather: 1 f32 DPP + 1 cvt_pk + 3 packed DPP (XOR commutes with packing)
        const float    hx  = dpp_movf<QP_X1>(h);
        const unsigned Ah0 = pack2(h, hx);                  // (h_u,   h_u^1)
        const unsigned Ah1 = dpp_movu<QP_X2>(Ah0);          // (h_u^2, h_u^3)
        const unsigned Ah2 = dpp_movu<ROW_ROR8>(Ah0);       // (h_u^4, h_u^5)
        const unsigned Ah3 = dpp_movu<ROW_ROR8>(Ah1);       // (h_u^6, h_u^7)

        // h-part: 4 parallel 4-deep dot2 chains
        float aI = AXI, aF = AXF, aG = AXG, aO = AXO;
        dot2(aI, whi[0], Ah0); dot2(aI, whi[1], Ah1); dot2(aI, whi[2], Ah2); dot2(aI, whi[3], Ah3);
        dot2(aF, whf[0], Ah0); dot2(aF, whf[1], Ah1); dot2(aF, whf[2], Ah2); dot2(aF, whf[3], Ah3);
        dot2(aG, whg[0], Ah0); dot2(aG, whg[1], Ah1); dot2(aG, whg[2], Ah2); dot2(aG, whg[3], Ah3);
        dot2(aO, who[0], Ah0); dot2(aO, who[1], Ah1); dot2(aO, who[2], Ah2); dot2(aO, who[3], Ah3);

        // x-part for step t+1 (independent filler for the act chains)
        NXI = bi; NXF = bfv; NXG = bg; NXO = bo;
        dot2(NXI, wxi[0], RS0); dot2(NXI, wxi[1], RS1); dot2(NXI, wxi[2], RS2);
        dot2(NXF, wxf[0], RS0); dot2(NXF, wxf[1], RS1); dot2(NXF, wxf[2], RS2);
        dot2(NXG, wxg[0], RS0); dot2(NXG, wxg[1], RS1); dot2(NXG, wxg[2], RS2);
        dot2(NXO, wxo[0], RS0); dot2(NXO, wxo[1], RS1); dot2(NXO, wxo[2], RS2);

        // fused activations: 5 exp2 + 2 rcp total
        // A=e^-ri, E=e^-rf, B=e^-2rg, C=e^-ro (preacts pre-scaled)
        const float A  = exp2_hw(aI), E = exp2_hw(aF), B = exp2_hw(aG), Cv = exp2_hw(aO);
        const float a1 = 1.0f + A, b1 = 1.0f + B, e1 = 1.0f + E, c1 = 1.0f + Cv;
        const float P  = a1 * b1;
        const float Q  = P * e1;
        const float t1 = (1.0f - B) * e1;
        const float num = fmaf(c, P, t1);
        c = num * rcp_hw(Q);                       // c' = f*c + i*g
        const float D  = exp2_hw(c * SGG);         // e^{-2c'}
        h = (1.0f - D) * rcp_hw(c1 * (1.0f + D));  // o * tanh(c')
    };

    for (int ck = 0; ck < NCHUNK; ++ck) {
        const int nxt = BUFD - cur;
        // issue fill loads for chunk ck+1 early; convert+write late (T14 split)
        f32x2 st0, st1, st2, st3, st4, st5;
        if (ck < NCHUNK - 1) {
            const int adv = (ck + 1) * (CHUNK * 6);
            st0 = *(const f32x2*)(fg[0] + adv); st1 = *(const f32x2*)(fg[1] + adv);
            st2 = *(const f32x2*)(fg[2] + adv); st3 = *(const f32x2*)(fg[3] + adv);
            st4 = *(const f32x2*)(fg[4] + adv); st5 = *(const f32x2*)(fg[5] + adv);
        }
        STEP(axiA,axfA,axgA,axoA, axiB,axfB,axgB,axoB, sB0,sB1,sB2, sA0,sA1,sA2, cur +  2*ROWD + rb);
        STEP(axiB,axfB,axgB,axoB, axiA,axfA,axgA,axoA, sA0,sA1,sA2, sB0,sB1,sB2, cur +  3*ROWD + rb);
        STEP(axiA,axfA,axgA,axoA, axiB,axfB,axgB,axoB, sB0,sB1,sB2, sA0,sA1,sA2, cur +  4*ROWD + rb);
        STEP(axiB,axfB,axgB,axoB, axiA,axfA,axgA,axoA, sA0,sA1,sA2, sB0,sB1,sB2, cur +  5*ROWD + rb);
        STEP(axiA,axfA,axgA,axoA, axiB,axfB,axgB,axoB, sB0,sB1,sB2, sA0,sA1,sA2, cur +  6*ROWD + rb);
        STEP(axiB,axfB,axgB,axoB, axiA,axfA,axgA,axoA, sA0,sA1,sA2, sB0,sB1,sB2, cur +  7*ROWD + rb);
        STEP(axiA,axfA,axgA,axoA, axiB,axfB,axgB,axoB, sB0,sB1,sB2, sA0,sA1,sA2, cur +  8*ROWD + rb);
        STEP(axiB,axfB,axgB,axoB, axiA,axfA,axgA,axoA, sA0,sA1,sA2, sB0,sB1,sB2, cur +  9*ROWD + rb);
        STEP(axiA,axfA,axgA,axoA, axiB,axfB,axgB,axoB, sB0,sB1,sB2, sA0,sA1,sA2, cur + 10*ROWD + rb);
        STEP(axiB,axfB,axgB,axoB, axiA,axfA,axgA,axoA, sA0,sA1,sA2, sB0,sB1,sB2, cur + 11*ROWD + rb);
        STEP(axiA,axfA,axgA,axoA, axiB,axfB,axgB,axoB, sB0,sB1,sB2, sA0,sA1,sA2, cur + 12*ROWD + rb);
        STEP(axiB,axfB,axgB,axoB, axiA,axfA,axgA,axoA, sA0,sA1,sA2, sB0,sB1,sB2, cur + 13*ROWD + rb);
        STEP(axiA,axfA,axgA,axoA, axiB,axfB,axgB,axoB, sB0,sB1,sB2, sA0,sA1,sA2, cur + 14*ROWD + rb);
        STEP(axiB,axfB,axgB,axoB, axiA,axfA,axgA,axoA, sA0,sA1,sA2, sB0,sB1,sB2, cur + 15*ROWD + rb);
        if (ck < NCHUNK - 1) {
            lds[fw[0] + nxt] = pack2(st0.x, st0.y);
            lds[fw[1] + nxt] = pack2(st1.x, st1.y);
            lds[fw[2] + nxt] = pack2(st2.x, st2.y);
            lds[fw[3] + nxt] = pack2(st3.x, st3.y);
            lds[fw[4] + nxt] = pack2(st4.x, st4.y);
            lds[fw[5] + nxt] = pack2(st5.x, st5.y);
        }
        __syncthreads();
        STEP(axiA,axfA,axgA,axoA, axiB,axfB,axgB,axoB, sB0,sB1,sB2, sA0,sA1,sA2, nxt + 0*ROWD + rb);
        STEP(axiB,axfB,axgB,axoB, axiA,axfA,axgA,axoA, sA0,sA1,sA2, sB0,sB1,sB2, nxt + 1*ROWD + rb);
        cur = nxt;
    }

    // ---- head: f32 all-gather (7 DPP, once), 6->4->2->softmax ----
    const float g1 = dpp_movf<QP_X1>(h);
    const float g2 = dpp_movf<QP_X2>(h);
    const float g3 = dpp_movf<QP_X2>(g1);
    const float g4 = dpp_movf<ROW_ROR8>(h);
    const float g5 = dpp_movf<ROW_ROR8>(g1);
    const float g6 = dpp_movf<ROW_ROR8>(g2);
    const float g7 = dpp_movf<ROW_ROR8>(g3);
    const float arr[8] = {h, g1, g2, g3, g4, g5, g6, g7};

    float o1[4];
    #pragma unroll
    for (int m = 0; m < 4; ++m) {
        float a = b1v[m];
        #pragma unroll
        for (int j = 0; j < 8; ++j) {
            const int v  = u ^ j;
            const int vi = (v < 6) ? v : 0;
            const float w = (v < 6) ? W1[m * 6 + vi] : 0.0f;
            a = fmaf(w, arr[j], a);
        }
        o1[m] = a;
    }
    float o2[2];
    #pragma unroll
    for (int m = 0; m < 2; ++m) {
        float a = b2v[m];
        #pragma unroll
        for (int j = 0; j < 4; ++j) a = fmaf(W2[m * 4 + j], o1[j], a);
        o2[m] = a;
    }
    const float mx  = fmaxf(o2[0], o2[1]);
    const float e0s = exp2_hw((o2[0] - mx) * L2E);
    const float e1s = exp2_hw((o2[1] - mx) * L2E);
    const float sc  = rcp_hw(e0s + e1s);

    if (u == 0) {
        ((float2*)out)[b] = make_float2(e0s * sc, e1s * sc);
    }
}

extern "C" void kernel_launch(void* const* d_in, const int* in_sizes, int n_in,
                              void* d_out, int out_size, void* d_ws, size_t ws_size,
                              hipStream_t stream) {
    const float* x   = (const float*)d_in[0];
    const float* Wih = (const float*)d_in[1];
    const float* Whh = (const float*)d_in[2];
    const float* bih = (const float*)d_in[3];
    const float* bhh = (const float*)d_in[4];
    const float* W1  = (const float*)d_in[5];
    const float* b1v = (const float*)d_in[6];
    const float* W2  = (const float*)d_in[7];
    const float* b2v = (const float*)d_in[8];
    float* out = (float*)d_out;

    // 8-lane XOR groups, 8 batches/wave, 4 waves/block -> 32 batch/block
    // -> 256 blocks = 1024 waves = 1 wave/SIMD on 256 CUs.
    const int blocks = BATCH / 32;
    lstm_r7_kernel<<<blocks, 256, 0, stream>>>(x, Wih, Whh, bih, bhh, W1, b1v, W2, b2v, out);
}

// Round 10
// 85.791 us; speedup vs baseline: 1.7294x; 1.0005x over previous
//
#include <hip/hip_runtime.h>

#define T_STEPS 512
#define BATCH   8192
#define CHUNK   16
#define NCHUNK  (T_STEPS / CHUNK)   // 32
#define ROWD    128                  // dwords per step-row (32 batches x 4)
#define BUFD    (CHUNK * ROWD)       // 2048 dwords per buffer

typedef float f32x2 __attribute__((ext_vector_type(2)));

#define L2E 1.4426950408889634f

__device__ __forceinline__ float rcp_hw(float v)  { return __builtin_amdgcn_rcpf(v); }
__device__ __forceinline__ float exp2_hw(float v) { return __builtin_amdgcn_exp2f(v); }

// DPP cross-lane move (VALU pipe). CTRL compile-time.
template<int CTRL>
__device__ __forceinline__ unsigned dpp_movu(unsigned v) {
    return (unsigned)__builtin_amdgcn_mov_dpp((int)v, CTRL, 0xF, 0xF, true);
}
template<int CTRL>
__device__ __forceinline__ float dpp_movf(float v) {
    return __int_as_float(__builtin_amdgcn_mov_dpp(__float_as_int(v), CTRL, 0xF, 0xF, true));
}
#define QP_X1    0xB1   // quad_perm [1,0,3,2] : lane^1
#define QP_X2    0x4E   // quad_perm [2,3,0,1] : lane^2
#define ROW_ROR8 0x128  // row_ror:8          : lane^8 (== XOR8 in 16-lane row)

// pack two f32 into one dword of f16 pairs (RTZ)
__device__ __forceinline__ unsigned pack2(float a, float b) {
    auto t = __builtin_amdgcn_cvt_pkrtz(a, b);   // __fp16 ext_vector_type(2)
    return __builtin_bit_cast(unsigned int, t);
}
// acc += dot(f16pair w, f16pair v)  -- f32 accumulate
__device__ __forceinline__ void dot2(float& acc, unsigned w, unsigned v) {
    asm("v_dot2_f32_f16 %0, %1, %2, %0" : "+v"(acc) : "v"(w), "v"(v));
}

__global__ __launch_bounds__(256) void lstm_r7_kernel(
    const float* __restrict__ x,   const float* __restrict__ Wih,
    const float* __restrict__ Whh, const float* __restrict__ bih,
    const float* __restrict__ bhh, const float* __restrict__ W1,
    const float* __restrict__ b1v, const float* __restrict__ W2,
    const float* __restrict__ b2v, float* __restrict__ out)
{
    __shared__ unsigned lds[2 * BUFD];   // 16 KB, x as packed f16 pairs

    const int tid  = threadIdx.x;
    const int lane = tid & 63;
    const int r    = lane & 15;                    // row-local lane
    const int u    = (r & 3) | ((r >> 1) & 4);     // slot 0..7 in XOR group {^1,^2,^8}
    const int d    = (u < 6) ? u : u - 2;          // unit owned (slots 6,7 dup 4,5)
    const int grp  = ((lane >> 4) << 1) | ((lane >> 2) & 1);
    const int bl   = ((tid >> 6) << 3) | grp;      // block-local batch 0..31
    const int b    = blockIdx.x * 32 + bl;

    const int ri = d, rf = 6 + d, rg = 12 + d, ro = 18 + d;
    const float SIF = -L2E;          // sigmoid pre-scale (i,f,o)
    const float SGG = -2.0f * L2E;   // tanh pre-scale (g)

    // ---- packed f16 weights (pre-scaled so exp2 consumes preacts directly) ----
    unsigned wxi[3], wxf[3], wxg[3], wxo[3];
    #pragma unroll
    for (int k = 0; k < 3; ++k) {
        wxi[k] = pack2(SIF * Wih[ri*6 + 2*k], SIF * Wih[ri*6 + 2*k + 1]);
        wxf[k] = pack2(SIF * Wih[rf*6 + 2*k], SIF * Wih[rf*6 + 2*k + 1]);
        wxg[k] = pack2(SGG * Wih[rg*6 + 2*k], SGG * Wih[rg*6 + 2*k + 1]);
        wxo[k] = pack2(SIF * Wih[ro*6 + 2*k], SIF * Wih[ro*6 + 2*k + 1]);
    }
    unsigned whi[4], whf[4], whg[4], who[4];
    #pragma unroll
    for (int j = 0; j < 4; ++j) {
        const int v0 = u ^ (2*j), v1 = u ^ (2*j + 1);
        const float z = 0.0f;
        whi[j] = pack2(v0 < 6 ? SIF*Whh[ri*6 + v0] : z, v1 < 6 ? SIF*Whh[ri*6 + v1] : z);
        whf[j] = pack2(v0 < 6 ? SIF*Whh[rf*6 + v0] : z, v1 < 6 ? SIF*Whh[rf*6 + v1] : z);
        whg[j] = pack2(v0 < 6 ? SGG*Whh[rg*6 + v0] : z, v1 < 6 ? SGG*Whh[rg*6 + v1] : z);
        who[j] = pack2(v0 < 6 ? SIF*Whh[ro*6 + v0] : z, v1 < 6 ? SIF*Whh[ro*6 + v1] : z);
    }
    const float bi = SIF * (bih[ri] + bhh[ri]);
    const float bfv = SIF * (bih[rf] + bhh[rf]);
    const float bg = SGG * (bih[rg] + bhh[rg]);
    const float bo = SIF * (bih[ro] + bhh[ro]);

    // ---- cooperative x fill: 1536 pair-dwords/chunk = 256 thr x 6 ----
    const float* fg[6]; int fw[6];
    #pragma unroll
    for (int k = 0; k < 6; ++k) {
        const int j   = tid + k * 256;
        const int st  = j / 96;
        const int rem = j - st * 96;
        const int b2  = rem / 3;
        const int off = rem - b2 * 3;
        fg[k] = x + ((size_t)(blockIdx.x * 32 + b2) * T_STEPS + st) * 6 + off * 2;
        fw[k] = st * ROWD + b2 * 4 + off;
        f32x2 v = *(const f32x2*)fg[k];
        lds[fw[k]] = pack2(v.x, v.y);       // chunk 0 -> buffer 0
    }
    __syncthreads();

    int cur = 0;
    const int rb = bl * 4;

    // preload x(0), x(1) (all 8 lanes of a group read same address -> broadcast)
    unsigned sA0 = lds[rb],        sA1 = lds[rb + 1],        sA2 = lds[rb + 2];
    unsigned sB0 = lds[ROWD + rb], sB1 = lds[ROWD + rb + 1], sB2 = lds[ROWD + rb + 2];

    // x-part for step 0
    float axiA = bi, axfA = bfv, axgA = bg, axoA = bo;
    dot2(axiA, wxi[0], sA0); dot2(axiA, wxi[1], sA1); dot2(axiA, wxi[2], sA2);
    dot2(axfA, wxf[0], sA0); dot2(axfA, wxf[1], sA1); dot2(axfA, wxf[2], sA2);
    dot2(axgA, wxg[0], sA0); dot2(axgA, wxg[1], sA1); dot2(axgA, wxg[2], sA2);
    dot2(axoA, wxo[0], sA0); dot2(axoA, wxo[1], sA1); dot2(axoA, wxo[2], sA2);
    float axiB, axfB, axgB, axoB;

    float c = 0.0f, h = 0.0f;

    auto STEP = [&](float& AXI, float& AXF, float& AXG, float& AXO,
                    float& NXI, float& NXF, float& NXG, float& NXO,
                    unsigned RS0, unsigned RS1, unsigned RS2,
                    unsigned& WS0, unsigned& WS1, unsigned& WS2, int rdaddr) {
        // ds_read x(t+2), consumed next step (~1 step of latency cover)
        WS0 = lds[rdaddr]; WS1 = lds[rdaddr + 1]; WS2 = lds[rdaddr + 2];

        // h gather: 1 f32 DPP + 1 cvt_pk + 3 packed DPP (XOR commutes with packing)
        const float    hx  = dpp_movf<QP_X1>(h);
        const unsigned Ah0 = pack2(h, hx);                  // (h_u,   h_u^1)
        const unsigned Ah1 = dpp_movu<QP_X2>(Ah0);          // (h_u^2, h_u^3)
        const unsigned Ah2 = dpp_movu<ROW_ROR8>(Ah0);       // (h_u^4, h_u^5)
        const unsigned Ah3 = dpp_movu<ROW_ROR8>(Ah1);       // (h_u^6, h_u^7)

        // h-part: 4 parallel 4-deep dot2 chains
        float aI = AXI, aF = AXF, aG = AXG, aO = AXO;
        dot2(aI, whi[0], Ah0); dot2(aI, whi[1], Ah1); dot2(aI, whi[2], Ah2); dot2(aI, whi[3], Ah3);
        dot2(aF, whf[0], Ah0); dot2(aF, whf[1], Ah1); dot2(aF, whf[2], Ah2); dot2(aF, whf[3], Ah3);
        dot2(aG, whg[0], Ah0); dot2(aG, whg[1], Ah1); dot2(aG, whg[2], Ah2); dot2(aG, whg[3], Ah3);
        dot2(aO, who[0], Ah0); dot2(aO, who[1], Ah1); dot2(aO, who[2], Ah2); dot2(aO, who[3], Ah3);

        // x-part for step t+1 (independent filler for the act chains)
        NXI = bi; NXF = bfv; NXG = bg; NXO = bo;
        dot2(NXI, wxi[0], RS0); dot2(NXI, wxi[1], RS1); dot2(NXI, wxi[2], RS2);
        dot2(NXF, wxf[0], RS0); dot2(NXF, wxf[1], RS1); dot2(NXF, wxf[2], RS2);
        dot2(NXG, wxg[0], RS0); dot2(NXG, wxg[1], RS1); dot2(NXG, wxg[2], RS2);
        dot2(NXO, wxo[0], RS0); dot2(NXO, wxo[1], RS1); dot2(NXO, wxo[2], RS2);

        // fused activations: 5 exp2 + 2 rcp total
        // A=e^-ri, E=e^-rf, B=e^-2rg, C=e^-ro (preacts pre-scaled)
        const float A  = exp2_hw(aI), E = exp2_hw(aF), B = exp2_hw(aG), Cv = exp2_hw(aO);
        const float a1 = 1.0f + A, b1 = 1.0f + B, e1 = 1.0f + E, c1 = 1.0f + Cv;
        const float P  = a1 * b1;
        const float Q  = P * e1;
        const float t1 = (1.0f - B) * e1;
        const float num = fmaf(c, P, t1);
        c = num * rcp_hw(Q);                       // c' = f*c + i*g
        const float D  = exp2_hw(c * SGG);         // e^{-2c'}
        h = (1.0f - D) * rcp_hw(c1 * (1.0f + D));  // o * tanh(c')
    };

    for (int ck = 0; ck < NCHUNK; ++ck) {
        const int nxt = BUFD - cur;
        // issue fill loads for chunk ck+1 early; convert+write late (T14 split)
        f32x2 st0, st1, st2, st3, st4, st5;
        if (ck < NCHUNK - 1) {
            const int adv = (ck + 1) * (CHUNK * 6);
            st0 = *(const f32x2*)(fg[0] + adv); st1 = *(const f32x2*)(fg[1] + adv);
            st2 = *(const f32x2*)(fg[2] + adv); st3 = *(const f32x2*)(fg[3] + adv);
            st4 = *(const f32x2*)(fg[4] + adv); st5 = *(const f32x2*)(fg[5] + adv);
        }
        STEP(axiA,axfA,axgA,axoA, axiB,axfB,axgB,axoB, sB0,sB1,sB2, sA0,sA1,sA2, cur +  2*ROWD + rb);
        STEP(axiB,axfB,axgB,axoB, axiA,axfA,axgA,axoA, sA0,sA1,sA2, sB0,sB1,sB2, cur +  3*ROWD + rb);
        STEP(axiA,axfA,axgA,axoA, axiB,axfB,axgB,axoB, sB0,sB1,sB2, sA0,sA1,sA2, cur +  4*ROWD + rb);
        STEP(axiB,axfB,axgB,axoB, axiA,axfA,axgA,axoA, sA0,sA1,sA2, sB0,sB1,sB2, cur +  5*ROWD + rb);
        STEP(axiA,axfA,axgA,axoA, axiB,axfB,axgB,axoB, sB0,sB1,sB2, sA0,sA1,sA2, cur +  6*ROWD + rb);
        STEP(axiB,axfB,axgB,axoB, axiA,axfA,axgA,axoA, sA0,sA1,sA2, sB0,sB1,sB2, cur +  7*ROWD + rb);
        STEP(axiA,axfA,axgA,axoA, axiB,axfB,axgB,axoB, sB0,sB1,sB2, sA0,sA1,sA2, cur +  8*ROWD + rb);
        STEP(axiB,axfB,axgB,axoB, axiA,axfA,axgA,axoA, sA0,sA1,sA2, sB0,sB1,sB2, cur +  9*ROWD + rb);
        STEP(axiA,axfA,axgA,axoA, axiB,axfB,axgB,axoB, sB0,sB1,sB2, sA0,sA1,sA2, cur + 10*ROWD + rb);
        STEP(axiB,axfB,axgB,axoB, axiA,axfA,axgA,axoA, sA0,sA1,sA2, sB0,sB1,sB2, cur + 11*ROWD + rb);
        STEP(axiA,axfA,axgA,axoA, axiB,axfB,axgB,axoB, sB0,sB1,sB2, sA0,sA1,sA2, cur + 12*ROWD + rb);
        STEP(axiB,axfB,axgB,axoB, axiA,axfA,axgA,axoA, sA0,sA1,sA2, sB0,sB1,sB2, cur + 13*ROWD + rb);
        STEP(axiA,axfA,axgA,axoA, axiB,axfB,axgB,axoB, sB0,sB1,sB2, sA0,sA1,sA2, cur + 14*ROWD + rb);
        STEP(axiB,axfB,axgB,axoB, axiA,axfA,axgA,axoA, sA0,sA1,sA2, sB0,sB1,sB2, cur + 15*ROWD + rb);
        if (ck < NCHUNK - 1) {
            lds[fw[0] + nxt] = pack2(st0.x, st0.y);
            lds[fw[1] + nxt] = pack2(st1.x, st1.y);
            lds[fw[2] + nxt] = pack2(st2.x, st2.y);
            lds[fw[3] + nxt] = pack2(st3.x, st3.y);
            lds[fw[4] + nxt] = pack2(st4.x, st4.y);
            lds[fw[5] + nxt] = pack2(st5.x, st5.y);
        }
        __syncthreads();
        STEP(axiA,axfA,axgA,axoA, axiB,axfB,axgB,axoB, sB0,sB1,sB2, sA0,sA1,sA2, nxt + 0*ROWD + rb);
        STEP(axiB,axfB,axgB,axoB, axiA,axfA,axgA,axoA, sA0,sA1,sA2, sB0,sB1,sB2, nxt + 1*ROWD + rb);
        cur = nxt;
    }

    // ---- head: f32 all-gather (7 DPP, once), 6->4->2->softmax ----
    const float g1 = dpp_movf<QP_X1>(h);
    const float g2 = dpp_movf<QP_X2>(h);
    const float g3 = dpp_movf<QP_X2>(g1);
    const float g4 = dpp_movf<ROW_ROR8>(h);
    const float g5 = dpp_movf<ROW_ROR8>(g1);
    const float g6 = dpp_movf<ROW_ROR8>(g2);
    const float g7 = dpp_movf<ROW_ROR8>(g3);
    const float arr[8] = {h, g1, g2, g3, g4, g5, g6, g7};

    float o1[4];
    #pragma unroll
    for (int m = 0; m < 4; ++m) {
        float a = b1v[m];
        #pragma unroll
        for (int j = 0; j < 8; ++j) {
            const int v  = u ^ j;
            const int vi = (v < 6) ? v : 0;
            const float w = (v < 6) ? W1[m * 6 + vi] : 0.0f;
            a = fmaf(w, arr[j], a);
        }
        o1[m] = a;
    }
    float o2[2];
    #pragma unroll
    for (int m = 0; m < 2; ++m) {
        float a = b2v[m];
        #pragma unroll
        for (int j = 0; j < 4; ++j) a = fmaf(W2[m * 4 + j], o1[j], a);
        o2[m] = a;
    }
    const float mx  = fmaxf(o2[0], o2[1]);
    const float e0s = exp2_hw((o2[0] - mx) * L2E);
    const float e1s = exp2_hw((o2[1] - mx) * L2E);
    const float sc  = rcp_hw(e0s + e1s);

    if (u == 0) {
        ((float2*)out)[b] = make_float2(e0s * sc, e1s * sc);
    }
}

extern "C" void kernel_launch(void* const* d_in, const int* in_sizes, int n_in,
                              void* d_out, int out_size, void* d_ws, size_t ws_size,
                              hipStream_t stream) {
    const float* x   = (const float*)d_in[0];
    const float* Wih = (const float*)d_in[1];
    const float* Whh = (const float*)d_in[2];
    const float* bih = (const float*)d_in[3];
    const float* bhh = (const float*)d_in[4];
    const float* W1  = (const float*)d_in[5];
    const float* b1v = (const float*)d_in[6];
    const float* W2  = (const float*)d_in[7];
    const float* b2v = (const float*)d_in[8];
    float* out = (float*)d_out;

    // 8-lane XOR groups, 8 batches/wave, 4 waves/block -> 32 batch/block
    // -> 256 blocks = 1024 waves = 1 wave/SIMD on 256 CUs.
    const int blocks = BATCH / 32;
    lstm_r7_kernel<<<blocks, 256, 0, stream>>>(x, Wih, Whh, bih, bhh, W1, b1v, W2, b2v, out);
}